// Round 9
// baseline (193.273 us; speedup 1.0000x reference)
//
#include <hip/hip_runtime.h>
#include <hip/hip_bf16.h>

// ContrastiveLoss: loss = mean_i [ logsumexp_j(logits[i,:]) - pos_sim[i,i] ]
// logits = [20*xn@tn^T | 20*xn@hn^T + I], rows normalized.
// Round 9: i8 MFMA, 256x128 block tile, wave = 128x64 (8x4 of 16x16x64).
//  - R8 accounting: measured 69.5us vs floors MFMA 17 / LDS 30 / L2-stage 30.
//    Bigger C-per-wave cuts staged L2 traffic 1.07GB->393MB and LDS
//    reads/MFMA 0.5->0.375 b128, halves barrier-drain count per CU.
//  - acc 128 AGPR + ~100 VGPR ~ 230 unified -> still 2 waves/SIMD; LDS
//    48KB/block -> 2 blocks/CU.
//  - Same verified i8 frag maps (16 contig bytes/lane) + zero-conflict
//    XOR chunk swizzle (phys = logical ^ (row&7)), R7/R8-measured 0.
//  - scaled-MFMA banned (R2/R4 VGPR blowup); b64 LDS reads banned (R5).

#define AS1 __attribute__((address_space(1)))
#define AS3 __attribute__((address_space(3)))

constexpr int N = 4096;
constexpr int D = 1024;            // elements per row == bytes per i8 row
constexpr float QSCALE = 127.0f;
constexpr float LSCALE = 20.0f / (127.0f * 127.0f);  // acc -> logit
constexpr float CBIAS = 21.0f;     // >= max possible logit (20*1 + 1)

typedef int i32x4 __attribute__((ext_vector_type(4)));

// 3072 blocks x 256. One row per wave; lane holds 16 CONTIGUOUS floats ->
// 16 int8 bytes -> one uint4 store at byte 16*lane (wave writes 1KB contig).
// Blocks 0..15 also zero rowsum so gemm's atomics start clean.
__global__ __launch_bounds__(256) void normalize_kernel(
    const float* __restrict__ in0, const float* __restrict__ in1,
    const float* __restrict__ in2, unsigned char* __restrict__ Abuf,
    unsigned char* __restrict__ Bbuf, float* __restrict__ rowsum) {
    const int t = threadIdx.x, lane = t & 63, wave = t >> 6;
    if (blockIdx.x < 16) rowsum[blockIdx.x * 256 + t] = 0.f;
    const int row = blockIdx.x * 4 + wave;  // 0..12287
    const int mat = row >> 12, r = row & (N - 1);
    const float* src = (mat == 0) ? in0 : (mat == 1) ? in1 : in2;
    unsigned char* dst = (mat == 0) ? (Abuf + (size_t)r * D)
                       : (mat == 1) ? (Bbuf + (size_t)r * D)
                                    : (Bbuf + (size_t)(r + N) * D);
    const float4* s4 = (const float4*)(src + (size_t)r * D);
    float4 v[4];
    float p = 0.f;
#pragma unroll
    for (int j = 0; j < 4; ++j) {
        v[j] = s4[4 * lane + j];  // floats 16*lane .. 16*lane+15
        p += v[j].x * v[j].x + v[j].y * v[j].y + v[j].z * v[j].z + v[j].w * v[j].w;
    }
#pragma unroll
    for (int m = 1; m < 64; m <<= 1) p += __shfl_xor(p, m);
    const float s = QSCALE / fmaxf(sqrtf(p), 1e-8f);
    uint4 o;
    unsigned int w[4];
#pragma unroll
    for (int j = 0; j < 4; ++j) {
        int q0 = min(127, max(-127, __float2int_rn(v[j].x * s)));
        int q1 = min(127, max(-127, __float2int_rn(v[j].y * s)));
        int q2 = min(127, max(-127, __float2int_rn(v[j].z * s)));
        int q3 = min(127, max(-127, __float2int_rn(v[j].w * s)));
        w[j] = (q0 & 255) | ((q1 & 255) << 8) | ((q2 & 255) << 16)
             | ((unsigned)(q3 & 255) << 24);
    }
    o.x = w[0]; o.y = w[1]; o.z = w[2]; o.w = w[3];
    ((uint4*)dst)[lane] = o;
}

// 256x128 tile, BK=128 i8-bytes. 4 waves in 2x2; wave computes 128x64 via
// 8x4 of 16x16x64 i8 MFMA (128 AGPR acc), 2 K-substeps per staged tile.
// A:[N,D] i8, B:[2N,D] i8, row-major. Frag: row = lane&15,
// k = (lane>>4)*16 + j (16 contiguous bytes -> one b128).
// C/D: col = lane&15, row = (lane>>4)*4 + reg (m89-verified).
__global__ __launch_bounds__(256) void gemm_lse_kernel(
    const unsigned char* __restrict__ A, const unsigned char* __restrict__ B,
    float* __restrict__ rowsum, float* __restrict__ posdiag) {
    __shared__ __align__(16) char As[256 * 128];  // 32 KiB
    __shared__ __align__(16) char Bs[128 * 128];  // 16 KiB

    const int tid = threadIdx.x;
    const int lane = tid & 63;
    const int wave = tid >> 6;
    const int wr = wave >> 1, wc = wave & 1;     // wave: rows wr*128, cols wc*64
    const int quad = lane >> 4, colid = lane & 15;
    const int rowBase = blockIdx.y * 256;
    const int colBase = blockIdx.x * 128;

    i32x4 acc[8][4];
#pragma unroll
    for (int i = 0; i < 8; ++i)
#pragma unroll
        for (int j = 0; j < 4; ++j) acc[i][j] = {0, 0, 0, 0};

    // Staging: A-tile 2048 16B-chunks (thread t fills t+256j, j=0..7),
    // B-tile 1024 (j=0..3). phys chunk c -> row c>>3, phys col c&7;
    // global logical col = (c&7) ^ (row&7)  (row&7 = (t>>3)&7, j-invariant).
    const int srow = tid >> 3;                      // 0..31
    const int scol = (tid & 7) ^ ((tid >> 3) & 7);  // 16B units
    const unsigned char* gA[8];
    const unsigned char* gB[4];
#pragma unroll
    for (int j = 0; j < 8; ++j)
        gA[j] = A + (size_t)(rowBase + srow + 32 * j) * D + scol * 16;
#pragma unroll
    for (int j = 0; j < 4; ++j)
        gB[j] = B + (size_t)(colBase + srow + 32 * j) * D + scol * 16;

    // Frag offsets: K-half h, row R: logical chunk h*4+quad, phys = log^(R&7).
    int aoff[8][2], boff[4][2];
#pragma unroll
    for (int rt = 0; rt < 8; ++rt) {
        const int R = wr * 128 + rt * 16 + colid;
#pragma unroll
        for (int h = 0; h < 2; ++h)
            aoff[rt][h] = R * 128 + ((h * 4 + quad) ^ (R & 7)) * 16;
    }
#pragma unroll
    for (int ct = 0; ct < 4; ++ct) {
        const int C = wc * 64 + ct * 16 + colid;
#pragma unroll
        for (int h = 0; h < 2; ++h)
            boff[ct][h] = C * 128 + ((h * 4 + quad) ^ (C & 7)) * 16;
    }

    for (int kb = 0; kb < D / 128; ++kb) {
        const int k0 = kb * 128;
        __syncthreads();  // prior reads done before overwrite
#pragma unroll
        for (int j = 0; j < 8; ++j)
            __builtin_amdgcn_global_load_lds((const AS1 void*)(gA[j] + k0),
                (AS3 void*)(As + (tid + 256 * j) * 16), 16, 0, 0);
#pragma unroll
        for (int j = 0; j < 4; ++j)
            __builtin_amdgcn_global_load_lds((const AS1 void*)(gB[j] + k0),
                (AS3 void*)(Bs + (tid + 256 * j) * 16), 16, 0, 0);
        __syncthreads();  // staged data visible

#pragma unroll
        for (int h = 0; h < 2; ++h) {
            i32x4 a[8], b[4];
#pragma unroll
            for (int rt = 0; rt < 8; ++rt)
                a[rt] = *(const i32x4*)(As + aoff[rt][h]);
#pragma unroll
            for (int ct = 0; ct < 4; ++ct)
                b[ct] = *(const i32x4*)(Bs + boff[ct][h]);
#pragma unroll
            for (int rt = 0; rt < 8; ++rt)
#pragma unroll
                for (int ct = 0; ct < 4; ++ct)
                    acc[rt][ct] = __builtin_amdgcn_mfma_i32_16x16x64_i8(
                        a[rt], b[ct], acc[rt][ct], 0, 0, 0);
        }
    }

    // Epilogue: C map col = lane&15, row = quad*4 + reg.
#pragma unroll
    for (int rt = 0; rt < 8; ++rt) {
        float rsum[4] = {0.f, 0.f, 0.f, 0.f};
#pragma unroll
        for (int ct = 0; ct < 4; ++ct) {
#pragma unroll
            for (int reg = 0; reg < 4; ++reg) {
                const int grow = rowBase + wr * 128 + rt * 16 + quad * 4 + reg;
                const int gcol = colBase + wc * 64 + ct * 16 + colid;
                float logit = (float)acc[rt][ct][reg] * LSCALE;
                if (gcol == grow + N) logit += 1.0f;      // hard-negative weight
                if (gcol == grow) posdiag[grow] = logit;  // unique writer
                rsum[reg] += __expf(logit - CBIAS);
            }
        }
#pragma unroll
        for (int reg = 0; reg < 4; ++reg) {
            float v = rsum[reg];
            v += __shfl_xor(v, 1);
            v += __shfl_xor(v, 2);
            v += __shfl_xor(v, 4);
            v += __shfl_xor(v, 8);
            if (colid == 0) {
                const int grow = rowBase + wr * 128 + rt * 16 + quad * 4 + reg;
                atomicAdd(&rowsum[grow], v);
            }
        }
    }
}

__global__ __launch_bounds__(256) void finalize_kernel(
    const float* __restrict__ rowsum, const float* __restrict__ posdiag,
    float* __restrict__ out) {
    const int t = threadIdx.x;
    float s = 0.f;
    for (int i = t; i < N; i += 256)
        s += CBIAS + logf(rowsum[i]) - posdiag[i];
    for (int m = 32; m; m >>= 1) s += __shfl_down(s, m);
    __shared__ float red[4];
    const int lane = t & 63, wave = t >> 6;
    if (lane == 0) red[wave] = s;
    __syncthreads();
    if (t == 0) out[0] = (red[0] + red[1] + red[2] + red[3]) / (float)N;
}

extern "C" void kernel_launch(void* const* d_in, const int* in_sizes, int n_in,
                              void* d_out, int out_size, void* d_ws, size_t ws_size,
                              hipStream_t stream) {
    const float* in0 = (const float*)d_in[0];  // input   [N, D] fp32
    const float* in1 = (const float*)d_in[1];  // target  [N, D] fp32
    const float* in2 = (const float*)d_in[2];  // hardneg [N, D] fp32

    // Workspace: Abuf N*D i8 (4 MiB) | Bbuf 2N*D i8 (8 MiB) | rowsum | posdiag
    unsigned char* Abuf = (unsigned char*)d_ws;
    unsigned char* Bbuf = Abuf + (size_t)N * D;
    float* rowsum = (float*)(Bbuf + (size_t)2 * N * D);
    float* posdiag = rowsum + N;

    normalize_kernel<<<3 * N / 4, 256, 0, stream>>>(in0, in1, in2, Abuf, Bbuf,
                                                    rowsum);
    gemm_lse_kernel<<<dim3(2 * N / 128, N / 256), 256, 0, stream>>>(
        Abuf, Bbuf, rowsum, posdiag);
    finalize_kernel<<<1, 256, 0, stream>>>(rowsum, posdiag, (float*)d_out);
}